// Round 1
// baseline (38.016 us; speedup 1.0000x reference)
//
#include <hip/hip_runtime.h>
#include <math.h>

#define SMALLF 1e-16f
#define EG 0.5772156649015329f

// digamma for x >= ~0.3 via recurrence shift +4 then Stirling asymptotic.
// psi(x) = psi(x+4) - sum_{k=0..3} 1/(x+k)
// psi(y) ~= ln(y) - 1/(2y) - 1/(12 y^2) + 1/(120 y^4) - 1/(252 y^6)
// At y >= 4.3 the truncation error is < 1e-6 -- far inside the 2e-2 tolerance.
__device__ __forceinline__ float fast_digamma(float x) {
    float s = 1.0f / x + 1.0f / (x + 1.0f) + 1.0f / (x + 2.0f) + 1.0f / (x + 3.0f);
    float y = x + 4.0f;
    float w = 1.0f / y;
    float w2 = w * w;
    float poly = w2 * (8.3333333333e-2f - w2 * (8.3333333333e-3f - w2 * 3.9682539683e-3f));
    return __logf(y) - 0.5f * w - poly - s;
}

// Full 11-term Kumaraswamy series (reference semantics). Only executed when
// beta != 1 (never in the benchmark inputs) -- kept __noinline__ so its 22
// lgammaf calls don't inflate hot-path VGPR use.
__device__ __noinline__ float kuma_series(float a, float b, float ab) {
    float ainv = 1.0f / (a + SMALLF);
    float lgb = lgammaf(b);
    // m = 1 term: B(1/a, b) / (1 + ab)
    float s = expf(lgammaf(ainv) + lgb - lgammaf(ainv + b)) / (1.0f + ab);
#pragma unroll 1
    for (int idx = 0; idx < 10; ++idx) {
        float m = (float)idx + 2.0f;
        float x = m * ainv;
        s += expf(lgammaf(x) + lgb - lgammaf(x + b)) / (m + ab);
    }
    return s;
}

__device__ __forceinline__ float kl_elem(float a, float b, float alpha, float betam1, float C) {
    float ab   = fmaf(a, b, SMALLF);
    float arcp = 1.0f / (a + SMALLF);
    float binv = 1.0f / (b + SMALLF);
    float psi  = fast_digamma(b + SMALLF);

    float kl = (a - alpha) * arcp * (-EG - psi - binv)   // digamma cross-term
             + __logf(ab)                                // log(ab)
             + C                                         // log(B(alpha,beta)+SMALL), hoisted
             + (1.0f - b) * binv;                        // -(b-1)/(b+SMALL)

    if (__builtin_expect(betam1 != 0.0f, 0)) {
        kl += betam1 * b * kuma_series(a, b, ab);        // zero when beta == 1
    }
    return kl;
}

// One-thread prep: hoist the uniform scalar work out of the 8.4M-element kernel.
__global__ void kl_prep(const float* __restrict__ alpha, const float* __restrict__ beta,
                        float* __restrict__ ws) {
    if (threadIdx.x == 0 && blockIdx.x == 0) {
        float al = alpha[0], be = beta[0];
        float lb = lgammaf(al) + lgammaf(be) - lgammaf(al + be);
        ws[0] = logf(expf(lb) + SMALLF);  // C
        ws[1] = al;                       // alpha
        ws[2] = be - 1.0f;                // beta - 1
    }
}

__global__ void __launch_bounds__(256)
kl_main(const float* __restrict__ A, const float* __restrict__ B,
        const float* __restrict__ ws, float* __restrict__ out, int n) {
    float C      = ws[0];
    float alpha  = ws[1];
    float betam1 = ws[2];

    int n4 = n >> 2;
    const float4* A4 = (const float4*)A;
    const float4* B4 = (const float4*)B;
    float4*       O4 = (float4*)out;

    int stride = gridDim.x * blockDim.x;
    for (int i = blockIdx.x * blockDim.x + threadIdx.x; i < n4; i += stride) {
        float4 av = A4[i];
        float4 bv = B4[i];
        float4 o;
        o.x = kl_elem(av.x, bv.x, alpha, betam1, C);
        o.y = kl_elem(av.y, bv.y, alpha, betam1, C);
        o.z = kl_elem(av.z, bv.z, alpha, betam1, C);
        o.w = kl_elem(av.w, bv.w, alpha, betam1, C);
        O4[i] = o;
    }

    // tail (n % 4 != 0) -- not hit for 4096*2048 but kept for correctness
    if (blockIdx.x == 0 && threadIdx.x == 0) {
        for (int k = n4 << 2; k < n; ++k)
            out[k] = kl_elem(A[k], B[k], alpha, betam1, C);
    }
}

extern "C" void kernel_launch(void* const* d_in, const int* in_sizes, int n_in,
                              void* d_out, int out_size, void* d_ws, size_t ws_size,
                              hipStream_t stream) {
    const float* a     = (const float*)d_in[0];
    const float* b     = (const float*)d_in[1];
    const float* alpha = (const float*)d_in[2];
    const float* beta  = (const float*)d_in[3];
    float* out = (float*)d_out;
    float* ws  = (float*)d_ws;
    int n = in_sizes[0];

    hipLaunchKernelGGL(kl_prep, dim3(1), dim3(1), 0, stream, alpha, beta, ws);

    int n4 = n >> 2;
    int blocks = (n4 + 255) / 256;
    if (blocks > 2048) blocks = 2048;
    if (blocks < 1) blocks = 1;
    hipLaunchKernelGGL(kl_main, dim3(blocks), dim3(256), 0, stream, a, b, ws, out, n);
}

// Round 2
// 22.297 us; speedup vs baseline: 1.7050x; 1.7050x over previous
//
#include <hip/hip_runtime.h>
#include <math.h>

#define SMALLF 1e-16f
#define EG 0.5772156649015329f

__device__ __forceinline__ float rcpf(float x) { return __builtin_amdgcn_rcpf(x); }

// digamma for x > 0.3 via shift +4 then Stirling asymptotic.
// psi(x) = psi(x+4) - sum_{k=0..3} 1/(x+k)
// The 4-term reciprocal sum is collapsed to ONE reciprocal:
//   1/x + 1/(x+3) = (2x+3)/t,  1/(x+1) + 1/(x+2) = (2x+3)/(t+2),  t = x(x+3)
//   => s = (2x+3)*(2t+2) / (t*(t+2))
// psi(y) ~= ln(y) - 1/(2y) - 1/(12 y^2) + 1/(120 y^4) - 1/(252 y^6); y >= 4.3
// truncation < 1e-6, far inside the 2e-2 tolerance.
__device__ __forceinline__ float fast_digamma(float x) {
    float t  = x * (x + 3.0f);
    float s  = (2.0f * x + 3.0f) * (2.0f * t + 2.0f) * rcpf(t * (t + 2.0f));
    float y  = x + 4.0f;
    float w  = rcpf(y);
    float w2 = w * w;
    float poly = w2 * (8.3333333333e-2f - w2 * (8.3333333333e-3f - w2 * 3.9682539683e-3f));
    return __logf(y) - 0.5f * w - poly - s;
}

// Full 11-term Kumaraswamy series (reference semantics). Executed only when
// beta != 1 (never in the benchmark inputs) -- __noinline__ keeps its 22
// lgammaf calls from inflating hot-path VGPR use.
__device__ __noinline__ float kuma_series(float a, float b, float ab) {
    float ainv = 1.0f / (a + SMALLF);
    float lgb = lgammaf(b);
    float s = expf(lgammaf(ainv) + lgb - lgammaf(ainv + b)) / (1.0f + ab);
#pragma unroll 1
    for (int idx = 0; idx < 10; ++idx) {
        float m = (float)idx + 2.0f;
        float x = m * ainv;
        s += expf(lgammaf(x) + lgb - lgammaf(x + b)) / (m + ab);
    }
    return s;
}

// Cold path for the per-thread scalar constants (general alpha/beta).
__device__ __noinline__ float2 scalar_consts_cold(float al, float be) {
    float lb = lgammaf(al) + lgammaf(be) - lgammaf(al + be);
    float2 r;
    r.x = logf(expf(lb) + SMALLF);  // C = log(B(alpha,beta) + SMALL)
    r.y = be - 1.0f;                // beta - 1
    return r;
}

__device__ __forceinline__ float kl_elem(float a, float b, float alpha, float betam1, float C) {
    float ab   = fmaf(a, b, SMALLF);
    float arcp = rcpf(a + SMALLF);
    float binv = rcpf(b + SMALLF);
    float psi  = fast_digamma(b + SMALLF);

    float kl = (a - alpha) * arcp * (-EG - psi - binv)   // digamma cross-term
             + __logf(ab)                                // log(ab)
             + C                                         // hoisted scalar
             + (1.0f - b) * binv;                        // -(b-1)/(b+SMALL)

    if (__builtin_expect(betam1 != 0.0f, 0)) {
        kl += betam1 * b * kuma_series(a, b, ab);        // zero when beta == 1
    }
    return kl;
}

__global__ void __launch_bounds__(256)
kl_main(const float* __restrict__ A, const float* __restrict__ B,
        const float* __restrict__ alphaP, const float* __restrict__ betaP,
        float* __restrict__ out, int n) {
    // Per-thread uniform scalars; L2-broadcast loads, uniform branch.
    float al = alphaP[0], be = betaP[0];
    float C, betam1;
    if (al == 1.0f && be == 1.0f) {
        // lgamma(1)=lgamma(2)=0 -> B(1,1)=1 -> C=log(1f+1e-16f)=log(1f)=0 exactly
        C = 0.0f;
        betam1 = 0.0f;
    } else {
        float2 r = scalar_consts_cold(al, be);
        C = r.x;
        betam1 = r.y;
    }

    int n4 = n >> 2;
    const float4* A4 = (const float4*)A;
    const float4* B4 = (const float4*)B;
    float4*       O4 = (float4*)out;

    int stride = gridDim.x * blockDim.x;
    for (int i = blockIdx.x * blockDim.x + threadIdx.x; i < n4; i += stride) {
        float4 av = A4[i];
        float4 bv = B4[i];
        float4 o;
        o.x = kl_elem(av.x, bv.x, al, betam1, C);
        o.y = kl_elem(av.y, bv.y, al, betam1, C);
        o.z = kl_elem(av.z, bv.z, al, betam1, C);
        o.w = kl_elem(av.w, bv.w, al, betam1, C);
        O4[i] = o;
    }

    // tail (n % 4 != 0) -- not hit for 4096*2048 but kept for correctness
    if (blockIdx.x == 0 && threadIdx.x == 0) {
        for (int k = n4 << 2; k < n; ++k)
            out[k] = kl_elem(A[k], B[k], al, betam1, C);
    }
}

extern "C" void kernel_launch(void* const* d_in, const int* in_sizes, int n_in,
                              void* d_out, int out_size, void* d_ws, size_t ws_size,
                              hipStream_t stream) {
    const float* a     = (const float*)d_in[0];
    const float* b     = (const float*)d_in[1];
    const float* alpha = (const float*)d_in[2];
    const float* beta  = (const float*)d_in[3];
    float* out = (float*)d_out;
    int n = in_sizes[0];

    int n4 = n >> 2;
    int blocks = (n4 + 255) / 256;
    if (blocks > 2048) blocks = 2048;
    if (blocks < 1) blocks = 1;
    hipLaunchKernelGGL(kl_main, dim3(blocks), dim3(256), 0, stream,
                       a, b, alpha, beta, out, n);
}